// Round 9
// baseline (385.435 us; speedup 1.0000x reference)
//
#include <hip/hip_runtime.h>
#include <hip/hip_fp16.h>
#include <math.h>

#define NN 30000          // nodes
#define NE 480000         // edges
#define FEA 16            // edge feature dim
#define HID 64
#define NG 64             // graphs
#define LEAKK 0.2f

// ---- small-constant region layout (float offsets) ----
#define S_AEL1   0    // 4: raw SUM over edges of a_e1 (scale by 1/NE on read)
#define S_AEL2   4    // 4
#define S_KF1    16   // 64  (K1 [16,4])
#define S_C1     80   // 4
#define S_KF2    88   // 64
#define S_C2     152  // 4
#define S_MS2    1184 // 256 (Ms2 [64,4])
#define S_MD2    1440 // 256
#define S_EAS    1700 // 16: EA column sums (atomic accum)

// ---- BT (transposed bf16 hi/lo weight) region layout (ushort offsets) ----
#define BT1H 0        // 64*320
#define BT1L 20480
#define BT2H 40960    // 64*256
#define BT2L 57344
#define BT3H 73728    // 64*128
#define BT3L 81920    // total 90112 ushorts == 45056 floats

// ---- cm_prepw block map (counts FIRST so the atomic long-pole spans the kernel) ----
#define B_CNT  469    // (NE+1023)/1024 count/rank blocks
#define B_BT   645    // +176 BT blocks
#define B_MS2  645    // MS2/MD2
#define B_KF   646    // KF/C
#define B_GOFF 647    // goff
#define B_EA0  648    // EA colsum [648,712)
#define B_ATT0 712    // attn blocks [712, 712+469)
#define B_TOT  1181

typedef __attribute__((ext_vector_type(8))) short short8;
typedef __attribute__((ext_vector_type(4))) float f32x4;

__device__ __forceinline__ float eluf(float v) { return v > 0.f ? v : expm1f(v); }
__device__ __forceinline__ float leakyf(float v) { return v >= 0.f ? v : LEAKK * v; }
__device__ __forceinline__ void fma4(float4& a, float w, const float4& x) {
    a.x += w * x.x; a.y += w * x.y; a.z += w * x.z; a.w += w * x.w;
}
// pack two floats into bf16x2 (RNE)
__device__ __forceinline__ unsigned bf16pack(float a, float b) {
    unsigned ua = __float_as_uint(a), ub = __float_as_uint(b);
    ua = (ua + 0x7FFFu + ((ua >> 16) & 1u)) >> 16;
    ub = (ub + 0x7FFFu + ((ub >> 16) & 1u)) >> 16;
    return ua | (ub << 16);
}
__device__ __forceinline__ unsigned short bf1(float v) {
    unsigned u = __float_as_uint(v);
    return (unsigned short)((u + 0x7FFFu + ((u >> 16) & 1u)) >> 16);
}
__device__ __forceinline__ float bf1tof(unsigned short h) {
    return __uint_as_float(((unsigned)h) << 16);
}
__device__ __forceinline__ uint2 bfpack4(float a, float b, float c, float d) {
    return make_uint2(bf16pack(a, b), bf16pack(c, d));
}
// unpack 4 bf16 (uint2) -> float4
__device__ __forceinline__ float4 bf16x4(uint2 p) {
    float4 r;
    r.x = __uint_as_float(p.x << 16);
    r.y = __uint_as_float(p.x & 0xFFFF0000u);
    r.z = __uint_as_float(p.y << 16);
    r.w = __uint_as_float(p.y & 0xFFFF0000u);
    return r;
}
// fp16 pack/unpack
__device__ __forceinline__ unsigned h2pack(float a, float b) {
    __half2 h = __floats2half2_rn(a, b);
    return *(unsigned*)&h;
}
__device__ __forceinline__ float2 h2unpack(unsigned u) {
    __half2 h = *(__half2*)&u;
    return __half22float2(h);
}
__device__ __forceinline__ float4 h4tof(uint2 p) {
    float2 lo = h2unpack(p.x), hi = h2unpack(p.y);
    return make_float4(lo.x, lo.y, hi.x, hi.y);
}
__device__ __forceinline__ float4 escore4(float4 a, float4 b, float4 c) {
    float4 r;
    r.x = expf(leakyf(a.x + b.x + c.x));
    r.y = expf(leakyf(a.y + b.y + c.y));
    r.z = expf(leakyf(a.z + b.z + c.z));
    r.w = expf(leakyf(a.w + b.w + c.w));
    return r;
}

// Edge record (32B): [0:8) w1 fp16x4; [8:16) ae2/w2 fp16x4; [16:20) sep; [20:24) dst; pad.
// cnt PADDED: counter n at cnt[n*8].

// ---- merged prep kernel: count atomics overlap attn/EA/BT work ----
__global__ __launch_bounds__(256) void cm_prepw_kernel(
    const int* __restrict__ dst, const float* __restrict__ EA,
    int* __restrict__ cnt, int* __restrict__ rank,
    const float* __restrict__ W1, const float* __restrict__ W2,
    const float* __restrict__ Wl, const float* __restrict__ Wr,
    const float* __restrict__ emb,
    const float* __restrict__ leW1, const float* __restrict__ aew1,
    const float* __restrict__ leW2, const float* __restrict__ aew2,
    const float* __restrict__ edge_W, const float* __restrict__ edge_b,
    const float* __restrict__ as1, const float* __restrict__ ad1,
    const float* __restrict__ as2, const float* __restrict__ ad2,
    const int* __restrict__ batch,
    const float* __restrict__ x, const float* __restrict__ node_emb,
    const int* __restrict__ node_type,
    unsigned short* __restrict__ BT, float* __restrict__ S, int* __restrict__ goff,
    float* __restrict__ as_, float* __restrict__ ad_, unsigned* __restrict__ xb) {
    __shared__ float xt[64 * 132];     // also reused as scratch by small blocks
    __shared__ float msS[512], mdS[512];
    __shared__ int ntS[64];
    int t = threadIdx.x, bx = blockIdx.x;
    if (bx < B_CNT) {                  // count/rank: 4 edges/thread, padded counters
        int base = bx * 1024;
        int e0 = base + t, e1 = e0 + 256, e2 = e0 + 512, e3 = e0 + 768;
        int d0 = (e0 < NE) ? dst[e0] : 0;
        int d1 = (e1 < NE) ? dst[e1] : 0;
        int d2 = (e2 < NE) ? dst[e2] : 0;
        int d3 = (e3 < NE) ? dst[e3] : 0;
        int r0 = 0, r1 = 0, r2 = 0, r3 = 0;
        if (e0 < NE) r0 = atomicAdd(&cnt[d0 * 8], 1);
        if (e1 < NE) r1 = atomicAdd(&cnt[d1 * 8], 1);
        if (e2 < NE) r2 = atomicAdd(&cnt[d2 * 8], 1);
        if (e3 < NE) r3 = atomicAdd(&cnt[d3 * 8], 1);
        if (e0 < NE) rank[e0] = r0;
        if (e1 < NE) rank[e1] = r1;
        if (e2 < NE) rank[e2] = r2;
        if (e3 < NE) rank[e3] = r3;
        return;
    }
    if (bx < B_BT) {                   // BT weight layout
        int i = (bx - B_CNT) * 256 + t;
        float v = 0.f;
        int dsti = -1;
        if (i < 16384) {               // BT1 x part: kk = h*64+k
            int kk = i >> 6, c = i & 63;
            int h = kk >> 6, k = kk & 63;
            v = 0.25f * W1[k * 256 + h * 64 + c];
            dsti = BT1H + c * 320 + kk;
        } else if (i < 20480) {        // BT1 emb part: kk = 256 + tau*4 + h
            int j2 = i - 16384;
            int r2 = j2 >> 6, c = j2 & 63;
            int tau = r2 >> 2, h = r2 & 3;
            float acc = 0.f;
            for (int j = 0; j < 64; j++)
                acc += emb[tau * 64 + j] * W1[(64 + j) * 256 + h * 64 + c];
            v = 0.25f * acc;
            dsti = BT1H + c * 320 + 256 + r2;
        } else if (i < 36864) {        // BT2
            int j = i - 20480;
            int kk = j >> 6, c = j & 63;
            int h = kk >> 6, k = kk & 63;
            v = 0.25f * W2[k * 256 + h * 64 + c];
            dsti = BT2H + c * 256 + kk;
        } else if (i < 45056) {        // BT3
            int j = i - 36864;
            int k = j >> 6, c = j & 63;
            v = (k < 64) ? Wl[k * 64 + c] : Wr[(k - 64) * 64 + c];
            dsti = BT3H + c * 128 + k;
        }
        if (dsti >= 0) {
            unsigned short hi = bf1(v);
            unsigned short lo = bf1(v - bf1tof(hi));
            BT[dsti] = hi;
            BT[dsti + 20480 - ((dsti >= BT2H) ? ((dsti >= BT3H) ? 12288 : 4096) : 0)] = lo;
        }
        return;
    }
    if (bx == B_MS2) {                 // MS2/MD2 (layer-2 attn fold for gemm DOATT)
        int k = t >> 2, h = t & 3;
        float s = 0.f, d = 0.f;
        for (int c = 0; c < 64; c++) {
            float w = W2[k * 256 + h * 64 + c];
            s += w * as2[h * 64 + c];
            d += w * ad2[h * 64 + c];
        }
        S[S_MS2 + t] = s; S[S_MD2 + t] = d;
        return;
    }
    if (bx == B_KF) {                  // KF/C build
        float* M1s = xt;               // reuse shared
        float* M2s = xt + 256;
        {
            int k = t >> 2, h = t & 3;
            float m1 = 0.f, m2 = 0.f;
            for (int c = 0; c < 64; c++) {
                m1 += leW1[k * 256 + h * 64 + c] * aew1[h * 64 + c];
                m2 += leW2[k * 256 + h * 64 + c] * aew2[h * 64 + c];
            }
            M1s[t] = m1; M2s[t] = m2;
        }
        __syncthreads();
        if (t < 64) {
            int f = t >> 2, h = t & 3;
            float k1 = 0.f, k2 = 0.f;
            for (int k = 0; k < 64; k++) {
                k1 += edge_W[f * 64 + k] * M1s[k * 4 + h];
                k2 += edge_W[f * 64 + k] * M2s[k * 4 + h];
            }
            S[S_KF1 + t] = k1; S[S_KF2 + t] = k2;
        } else if (t < 68) {
            int h = t - 64;
            float c1 = 0.f, c2 = 0.f;
            for (int k = 0; k < 64; k++) {
                c1 += edge_b[k] * M1s[k * 4 + h];
                c2 += edge_b[k] * M2s[k * 4 + h];
            }
            S[S_C1 + h] = c1; S[S_C2 + h] = c2;
        }
        return;
    }
    if (bx == B_GOFF) {                // goff
        if (t > NG) return;
        int lo = 0, hi = NN;
        while (lo < hi) {
            int mid = (lo + hi) >> 1;
            if (batch[mid] < t) lo = mid + 1; else hi = mid;
        }
        goff[t] = lo;
        return;
    }
    if (bx < B_ATT0) {                 // EA column sums: 64 blocks, 4x unrolled
        float4* red4 = (float4*)xt;
        int cb = bx - B_EA0;
        int c4 = (t & 3) * 4;
        int r0 = cb * 64 + (t >> 2);
        float4 a0 = {0, 0, 0, 0}, a1 = a0, a2 = a0, a3 = a0;
        for (int r = r0; r < NE; r += 16384) {
            int r1 = r + 4096, r2 = r + 8192, r3 = r + 12288;
            float4 v0 = *(const float4*)(EA + (size_t)r * FEA + c4);
            float4 v1 = (r1 < NE) ? *(const float4*)(EA + (size_t)r1 * FEA + c4)
                                  : make_float4(0, 0, 0, 0);
            float4 v2 = (r2 < NE) ? *(const float4*)(EA + (size_t)r2 * FEA + c4)
                                  : make_float4(0, 0, 0, 0);
            float4 v3 = (r3 < NE) ? *(const float4*)(EA + (size_t)r3 * FEA + c4)
                                  : make_float4(0, 0, 0, 0);
            a0.x += v0.x; a0.y += v0.y; a0.z += v0.z; a0.w += v0.w;
            a1.x += v1.x; a1.y += v1.y; a1.z += v1.z; a1.w += v1.w;
            a2.x += v2.x; a2.y += v2.y; a2.z += v2.z; a2.w += v2.w;
            a3.x += v3.x; a3.y += v3.y; a3.z += v3.z; a3.w += v3.w;
        }
        float4 acc;
        acc.x = (a0.x + a1.x) + (a2.x + a3.x);
        acc.y = (a0.y + a1.y) + (a2.y + a3.y);
        acc.z = (a0.z + a1.z) + (a2.z + a3.z);
        acc.w = (a0.w + a1.w) + (a2.w + a3.w);
#pragma unroll
        for (int mask = 4; mask < 64; mask <<= 1) {
            acc.x += __shfl_xor(acc.x, mask, 64);
            acc.y += __shfl_xor(acc.y, mask, 64);
            acc.z += __shfl_xor(acc.z, mask, 64);
            acc.w += __shfl_xor(acc.w, mask, 64);
        }
        int lane = t & 63, wid = t >> 6;
        if (lane < 4) red4[wid * 4 + lane] = acc;
        __syncthreads();
        if (t < 4) {
            float4 a = red4[t], b = red4[4 + t], c = red4[8 + t], d = red4[12 + t];
            atomicAdd(&S[S_EAS + t * 4 + 0], a.x + b.x + c.x + d.x);
            atomicAdd(&S[S_EAS + t * 4 + 1], a.y + b.y + c.y + d.y);
            atomicAdd(&S[S_EAS + t * 4 + 2], a.z + b.z + c.z + d.z);
            atomicAdd(&S[S_EAS + t * 4 + 3], a.w + b.w + c.w + d.w);
        }
        return;
    }
    // ---- attn blocks: x/emb load + xb cast + a_s/a_d (MS1/MD1 folded per-block) ----
    int n0 = (bx - B_ATT0) * 64;
    if (t < 64) {
        int n = n0 + t;
        ntS[t] = (n < NN) ? node_type[n] : 0;
    }
    for (int i = t; i < 512; i += 256) {   // redundant MS1/MD1 fold (W1 is L2-resident)
        int k = i >> 2, h = i & 3;
        float s = 0.f, d = 0.f;
        for (int c = 0; c < 64; c++) {
            float w = W1[k * 256 + h * 64 + c];
            s += w * as1[h * 64 + c];
            d += w * ad1[h * 64 + c];
        }
        msS[i] = s; mdS[i] = d;
    }
    __syncthreads();
    for (int i = t; i < 1024; i += 256) {
        int r = i >> 4, c4 = (i & 15) * 4;
        int n = n0 + r;
        float4 f = {0, 0, 0, 0};
        if (n < NN) f = *(const float4*)(x + (size_t)n * 64 + c4);
        *(float4*)&xt[r * 132 + c4] = f;
    }
    for (int i = t; i < 1024; i += 256) {
        int r = i >> 4, c4 = (i & 15) * 4;
        int n = n0 + r;
        float4 f = {0, 0, 0, 0};
        if (n < NN) f = *(const float4*)(node_emb + (size_t)ntS[r] * 64 + c4);
        *(float4*)&xt[r * 132 + 64 + c4] = f;
    }
    __syncthreads();
    for (int i = t; i < 2048; i += 256) {
        int r = i >> 5, u = i & 31;
        int n = n0 + r;
        if (n < NN)
            xb[(size_t)n * 32 + u] = bf16pack(xt[r * 132 + 2 * u], xt[r * 132 + 2 * u + 1]);
    }
    int r = t >> 2, h = t & 3;
    float s = 0.f, d = 0.f;
#pragma unroll 8
    for (int k = 0; k < 128; k++) {
        float xv = xt[r * 132 + k];
        s += xv * msS[k * 4 + h];
        d += xv * mdS[k * 4 + h];
    }
    int n = n0 + r;
    if (n < NN) { as_[n * 4 + h] = s; ad_[n * 4 + h] = d; }
}

// ---- 30-block scan over degree counts (padded cnt: stride 8) ----
__global__ void scan_blocks_kernel(const int* __restrict__ cnt, int* __restrict__ eoff,
                                   int* __restrict__ bsum) {
    __shared__ int wsum[16];
    int t = threadIdx.x;
    int i = blockIdx.x * 1024 + t;
    int v = (i < NN) ? cnt[i * 8] : 0;
    int lane = t & 63;
    int incl = v;
#pragma unroll
    for (int ofs = 1; ofs < 64; ofs <<= 1) {
        int u = __shfl_up(incl, ofs, 64);
        if (lane >= ofs) incl += u;
    }
    int wid = t >> 6;
    if (lane == 63) wsum[wid] = incl;
    __syncthreads();
    if (t < 16) {
        int s = wsum[t];
#pragma unroll
        for (int ofs = 1; ofs < 16; ofs <<= 1) {
            int u = __shfl_up(s, ofs, 64);
            if (t >= ofs) s += u;
        }
        wsum[t] = s;
    }
    __syncthreads();
    int excl = incl - v + (wid > 0 ? wsum[wid - 1] : 0);
    if (i < NN) eoff[i] = excl;
    if (t == 1023) bsum[blockIdx.x] = excl + v;
}

// ---- small: blocks 0..117 scan-add; block 118 AEL fold ----
__global__ __launch_bounds__(256) void scanadd_kernel(
    const int* __restrict__ bsum, int* __restrict__ eoff, float* __restrict__ S) {
    int t = threadIdx.x;
    if (blockIdx.x < 118) {
        int j = blockIdx.x >> 2;
        int pref = 0;
        for (int u = 0; u < j; u++) pref += bsum[u];
        int i = blockIdx.x * 256 + t;
        if (i < NN) eoff[i] += pref;
        if (i == 0) eoff[NN] = NE;
        return;
    }
    // AEL raw sums: sum_e a_e = KF^T * colsum(EA) + NE*C (linearity)
    if (t < 8) {
        int h = t & 3;
        const float* KF = (t < 4) ? (S + S_KF1) : (S + S_KF2);
        const float* C  = (t < 4) ? (S + S_C1)  : (S + S_C2);
        float acc = (float)NE * C[h];
        for (int f = 0; f < 16; f++) acc += S[S_EAS + f] * KF[f * 4 + h];
        S[((t < 4) ? S_AEL1 : S_AEL2) + h] = acc;
    }
}

// ---- scatter + edge projection + layer-1 scoring -> ONE 32B record per edge ----
__global__ __launch_bounds__(256) void scatter_proj_kernel(
    const int* __restrict__ src, const int* __restrict__ dst,
    const float* __restrict__ EA, const float* __restrict__ S,
    const float* __restrict__ as_, const float* __restrict__ ad_,
    const int* __restrict__ node_type,
    const int* __restrict__ eoff, const int* __restrict__ rank,
    uint4* __restrict__ recs) {
    __shared__ float KF1s[64], KF2s[64], Cs[8];
    int t = threadIdx.x;
    if (t < 64) { KF1s[t] = S[S_KF1 + t]; KF2s[t] = S[S_KF2 + t]; }
    else if (t < 72) { int q = t - 64; Cs[q] = (q < 4) ? S[S_C1 + q] : S[S_C2 + q - 4]; }
    __syncthreads();
    int e0 = blockIdx.x * 512 + t;
#pragma unroll
    for (int u = 0; u < 2; u++) {
        int e = e0 + u * 256;
        if (e < NE) {
            int s = src[e], d = dst[e];
            float a1[4], a2[4];
#pragma unroll
            for (int h = 0; h < 4; h++) { a1[h] = Cs[h]; a2[h] = Cs[4 + h]; }
            const float4* EA4 = (const float4*)(EA + (size_t)e * FEA);
#pragma unroll
            for (int q = 0; q < 4; q++) {
                float4 v = EA4[q];
                float vv[4] = {v.x, v.y, v.z, v.w};
#pragma unroll
                for (int j = 0; j < 4; j++) {
                    int f = q * 4 + j;
#pragma unroll
                    for (int h = 0; h < 4; h++) {
                        a1[h] += vv[j] * KF1s[f * 4 + h];
                        a2[h] += vv[j] * KF2s[f * 4 + h];
                    }
                }
            }
            int pos = eoff[d] + rank[e];
            float4 asv = ((const float4*)as_)[s];
            float4 adv = ((const float4*)ad_)[d];
            float4 w1 = escore4(asv, adv, make_float4(a1[0], a1[1], a1[2], a1[3]));
            uint4 lo = make_uint4(h2pack(w1.x, w1.y), h2pack(w1.z, w1.w),
                                  h2pack(a2[0], a2[1]), h2pack(a2[2], a2[3]));
            uint4 hi = make_uint4((unsigned)(s | (node_type[s] << 16)), (unsigned)d, 0u, 0u);
            recs[2 * pos] = lo;
            recs[2 * pos + 1] = hi;
        }
    }
}

// ---- layer-2 dense scoring, in-place in records; also emits compact sep for sage ----
__global__ __launch_bounds__(256) void score2_kernel(
    uint4* __restrict__ recs,
    const float* __restrict__ as_, const float* __restrict__ ad_,
    int* __restrict__ sepc) {
    int p = blockIdx.x * 256 + threadIdx.x;   // grid exact
    uint2 a2h = ((const uint2*)recs)[4 * p + 1];
    int2 sd = ((const int2*)recs)[4 * p + 2];
    int s = sd.x & 0xFFFF;
    float4 w2 = escore4(((const float4*)as_)[s], ((const float4*)ad_)[sd.y], h4tof(a2h));
    ((uint2*)recs)[4 * p + 1] = make_uint2(h2pack(w2.x, w2.y), h2pack(w2.z, w2.w));
    sepc[p] = sd.x;
}

// ---- layer-1 GAT aggregation: sorted records (w1 fp16) + bf16 x gather + type hist ----
__global__ __launch_bounds__(256) void agg_gat1_kernel(
    const int* __restrict__ eoff, const uint4* __restrict__ recs,
    const unsigned* __restrict__ xb,
    const int* __restrict__ node_type,
    const float* __restrict__ as_, const float* __restrict__ ad_,
    const float* __restrict__ S, uint2* __restrict__ aggb) {
    int n = blockIdx.x * 4 + (threadIdx.x >> 6);
    if (n >= NN) return;
    int lane = threadIdx.x & 63;
    int sub = lane >> 4, ch = lane & 15;
    const uint2* Xb = (const uint2*)xb;
    const int* RI = (const int*)recs;
    const uint2* RW = (const uint2*)recs;
    float4 asn = ((const float4*)as_)[n];
    float4 adn = ((const float4*)ad_)[n];
    float4 a0 = {0, 0, 0, 0}, a1 = a0, a2 = a0, a3 = a0, dn = a0, tw = a0;
    int b = eoff[n], e_end = eoff[n + 1];
    int nE = e_end - b;
    int i = sub;
    for (; i + 4 < nE; i += 8) {
        int p0 = b + i, p1 = p0 + 4;
        int q0 = RI[8 * p0 + 4], q1 = RI[8 * p1 + 4];
        int s0 = q0 & 0xFFFF, t0 = q0 >> 16;
        int s1 = q1 & 0xFFFF, t1 = q1 >> 16;
        float4 w0 = h4tof(RW[4 * p0]), w1 = h4tof(RW[4 * p1]);
        float4 x0 = bf16x4(Xb[(size_t)s0 * 16 + ch]);
        float4 x1 = bf16x4(Xb[(size_t)s1 * 16 + ch]);
        fma4(a0, w0.x, x0); fma4(a1, w0.y, x0); fma4(a2, w0.z, x0); fma4(a3, w0.w, x0);
        fma4(a0, w1.x, x1); fma4(a1, w1.y, x1); fma4(a2, w1.z, x1); fma4(a3, w1.w, x1);
        dn.x += w0.x + w1.x; dn.y += w0.y + w1.y;
        dn.z += w0.z + w1.z; dn.w += w0.w + w1.w;
        if (ch == t0) { tw.x += w0.x; tw.y += w0.y; tw.z += w0.z; tw.w += w0.w; }
        if (ch == t1) { tw.x += w1.x; tw.y += w1.y; tw.z += w1.z; tw.w += w1.w; }
    }
    for (; i < nE; i += 4) {
        int p0 = b + i;
        int q0 = RI[8 * p0 + 4];
        int s0 = q0 & 0xFFFF, t0 = q0 >> 16;
        float4 w0 = h4tof(RW[4 * p0]);
        float4 x0 = bf16x4(Xb[(size_t)s0 * 16 + ch]);
        fma4(a0, w0.x, x0); fma4(a1, w0.y, x0); fma4(a2, w0.z, x0); fma4(a3, w0.w, x0);
        dn.x += w0.x; dn.y += w0.y; dn.z += w0.z; dn.w += w0.w;
        if (ch == t0) { tw.x += w0.x; tw.y += w0.y; tw.z += w0.z; tw.w += w0.w; }
    }
    if (sub == 0) {  // self loop: Sael = raw sum / NE
        const float inv = 1.f / (float)NE;
        float e0 = expf(leakyf(asn.x + adn.x + S[S_AEL1 + 0] * inv));
        float e1 = expf(leakyf(asn.y + adn.y + S[S_AEL1 + 1] * inv));
        float e2 = expf(leakyf(asn.z + adn.z + S[S_AEL1 + 2] * inv));
        float e3 = expf(leakyf(asn.w + adn.w + S[S_AEL1 + 3] * inv));
        float4 xs = bf16x4(Xb[(size_t)n * 16 + ch]);
        fma4(a0, e0, xs); fma4(a1, e1, xs); fma4(a2, e2, xs); fma4(a3, e3, xs);
        dn.x += e0; dn.y += e1; dn.z += e2; dn.w += e3;
        int tn = node_type[n];
        if (ch == tn) { tw.x += e0; tw.y += e1; tw.z += e2; tw.w += e3; }
    }
#pragma unroll
    for (int mask = 16; mask < 64; mask <<= 1) {
        a0.x += __shfl_xor(a0.x, mask, 64); a0.y += __shfl_xor(a0.y, mask, 64);
        a0.z += __shfl_xor(a0.z, mask, 64); a0.w += __shfl_xor(a0.w, mask, 64);
        a1.x += __shfl_xor(a1.x, mask, 64); a1.y += __shfl_xor(a1.y, mask, 64);
        a1.z += __shfl_xor(a1.z, mask, 64); a1.w += __shfl_xor(a1.w, mask, 64);
        a2.x += __shfl_xor(a2.x, mask, 64); a2.y += __shfl_xor(a2.y, mask, 64);
        a2.z += __shfl_xor(a2.z, mask, 64); a2.w += __shfl_xor(a2.w, mask, 64);
        a3.x += __shfl_xor(a3.x, mask, 64); a3.y += __shfl_xor(a3.y, mask, 64);
        a3.z += __shfl_xor(a3.z, mask, 64); a3.w += __shfl_xor(a3.w, mask, 64);
        dn.x += __shfl_xor(dn.x, mask, 64); dn.y += __shfl_xor(dn.y, mask, 64);
        dn.z += __shfl_xor(dn.z, mask, 64); dn.w += __shfl_xor(dn.w, mask, 64);
        tw.x += __shfl_xor(tw.x, mask, 64); tw.y += __shfl_xor(tw.y, mask, 64);
        tw.z += __shfl_xor(tw.z, mask, 64); tw.w += __shfl_xor(tw.w, mask, 64);
    }
    if (sub == 0) {
        float i0 = 1.f / dn.x, i1 = 1.f / dn.y, i2 = 1.f / dn.z, i3 = 1.f / dn.w;
        uint2* A2 = aggb + (size_t)n * 80;   // 320 bf16 per node
        A2[ch]      = bfpack4(a0.x * i0, a0.y * i0, a0.z * i0, a0.w * i0);
        A2[16 + ch] = bfpack4(a1.x * i1, a1.y * i1, a1.z * i1, a1.w * i1);
        A2[32 + ch] = bfpack4(a2.x * i2, a2.y * i2, a2.z * i2, a2.w * i2);
        A2[48 + ch] = bfpack4(a3.x * i3, a3.y * i3, a3.z * i3, a3.w * i3);
        A2[64 + ch] = bfpack4(tw.x * i0, tw.y * i1, tw.z * i2, tw.w * i3);
    }
}

// ---- layer-2 GAT aggregation: sorted records (w2 fp16) + bf16 h1 gather ----
__global__ __launch_bounds__(256) void agg_gat2_kernel(
    const int* __restrict__ eoff, const uint4* __restrict__ recs,
    const unsigned* __restrict__ h1b,
    const float* __restrict__ as_, const float* __restrict__ ad_,
    const float* __restrict__ S, uint2* __restrict__ aggb) {
    int n = blockIdx.x * 4 + (threadIdx.x >> 6);
    if (n >= NN) return;
    int lane = threadIdx.x & 63;
    int sub = lane >> 4, ch = lane & 15;
    const uint2* Xb = (const uint2*)h1b;
    const int* RI = (const int*)recs;
    const uint2* RW = (const uint2*)recs;
    float4 asn = ((const float4*)as_)[n];
    float4 adn = ((const float4*)ad_)[n];
    float4 a0 = {0, 0, 0, 0}, a1 = a0, a2 = a0, a3 = a0, dn = a0;
    int b = eoff[n], e = eoff[n + 1];
    int nE = e - b;
    int i = sub;
    for (; i + 4 < nE; i += 8) {
        int p0 = b + i, p1 = p0 + 4;
        int s0 = RI[8 * p0 + 4] & 0xFFFF, s1 = RI[8 * p1 + 4] & 0xFFFF;
        float4 w0 = h4tof(RW[4 * p0 + 1]), w1 = h4tof(RW[4 * p1 + 1]);
        float4 x0 = bf16x4(Xb[(size_t)s0 * 16 + ch]);
        float4 x1 = bf16x4(Xb[(size_t)s1 * 16 + ch]);
        fma4(a0, w0.x, x0); fma4(a1, w0.y, x0); fma4(a2, w0.z, x0); fma4(a3, w0.w, x0);
        fma4(a0, w1.x, x1); fma4(a1, w1.y, x1); fma4(a2, w1.z, x1); fma4(a3, w1.w, x1);
        dn.x += w0.x + w1.x; dn.y += w0.y + w1.y;
        dn.z += w0.z + w1.z; dn.w += w0.w + w1.w;
    }
    for (; i < nE; i += 4) {
        int p0 = b + i;
        int s0 = RI[8 * p0 + 4] & 0xFFFF;
        float4 w0 = h4tof(RW[4 * p0 + 1]);
        float4 x0 = bf16x4(Xb[(size_t)s0 * 16 + ch]);
        fma4(a0, w0.x, x0); fma4(a1, w0.y, x0); fma4(a2, w0.z, x0); fma4(a3, w0.w, x0);
        dn.x += w0.x; dn.y += w0.y; dn.z += w0.z; dn.w += w0.w;
    }
    if (sub == 0) {  // self loop
        const float inv = 1.f / (float)NE;
        float e0 = expf(leakyf(asn.x + adn.x + S[S_AEL2 + 0] * inv));
        float e1 = expf(leakyf(asn.y + adn.y + S[S_AEL2 + 1] * inv));
        float e2 = expf(leakyf(asn.z + adn.z + S[S_AEL2 + 2] * inv));
        float e3 = expf(leakyf(asn.w + adn.w + S[S_AEL2 + 3] * inv));
        float4 xs = bf16x4(Xb[(size_t)n * 16 + ch]);
        fma4(a0, e0, xs); fma4(a1, e1, xs); fma4(a2, e2, xs); fma4(a3, e3, xs);
        dn.x += e0; dn.y += e1; dn.z += e2; dn.w += e3;
    }
#pragma unroll
    for (int mask = 16; mask < 64; mask <<= 1) {
        a0.x += __shfl_xor(a0.x, mask, 64); a0.y += __shfl_xor(a0.y, mask, 64);
        a0.z += __shfl_xor(a0.z, mask, 64); a0.w += __shfl_xor(a0.w, mask, 64);
        a1.x += __shfl_xor(a1.x, mask, 64); a1.y += __shfl_xor(a1.y, mask, 64);
        a1.z += __shfl_xor(a1.z, mask, 64); a1.w += __shfl_xor(a1.w, mask, 64);
        a2.x += __shfl_xor(a2.x, mask, 64); a2.y += __shfl_xor(a2.y, mask, 64);
        a2.z += __shfl_xor(a2.z, mask, 64); a2.w += __shfl_xor(a2.w, mask, 64);
        a3.x += __shfl_xor(a3.x, mask, 64); a3.y += __shfl_xor(a3.y, mask, 64);
        a3.z += __shfl_xor(a3.z, mask, 64); a3.w += __shfl_xor(a3.w, mask, 64);
        dn.x += __shfl_xor(dn.x, mask, 64); dn.y += __shfl_xor(dn.y, mask, 64);
        dn.z += __shfl_xor(dn.z, mask, 64); dn.w += __shfl_xor(dn.w, mask, 64);
    }
    if (sub == 0) {
        float i0 = 1.f / dn.x, i1 = 1.f / dn.y, i2 = 1.f / dn.z, i3 = 1.f / dn.w;
        uint2* A2 = aggb + (size_t)n * 64;   // 256 bf16 per node
        A2[ch]      = bfpack4(a0.x * i0, a0.y * i0, a0.z * i0, a0.w * i0);
        A2[16 + ch] = bfpack4(a1.x * i1, a1.y * i1, a1.z * i1, a1.w * i1);
        A2[32 + ch] = bfpack4(a2.x * i2, a2.y * i2, a2.z * i2, a2.w * i2);
        A2[48 + ch] = bfpack4(a3.x * i3, a3.y * i3, a3.z * i3, a3.w * i3);
    }
}

// ---- MFMA GEMM: out[M,64] = elu(A@B + bias). A bf16 rows; B = BT hi/lo bf16 (transposed).
template <int K, bool DOATT>
__global__ __launch_bounds__(256) void gemm_mfma_kernel(
    const unsigned* __restrict__ A, const unsigned short* __restrict__ bth,
    const unsigned short* __restrict__ btl,
    const float* __restrict__ bias, float* __restrict__ out,
    unsigned short* __restrict__ out16,
    const float* __restrict__ ms_g, const float* __restrict__ md_g,
    float* __restrict__ as_, float* __restrict__ ad_) {
    int t = threadIdx.x;
    int w = t >> 6, l = t & 63;
    int lr = l & 15, lg = l >> 4;
    int m0 = blockIdx.x * 64 + w * 16;
    int am = m0 + lr;
    bool av = am < NN;
    const short8* Arow = (const short8*)A + (size_t)am * (K / 8);
    short8 zz = {0, 0, 0, 0, 0, 0, 0, 0};
    f32x4 acc[4];
#pragma unroll
    for (int ct = 0; ct < 4; ct++) acc[ct] = (f32x4){0.f, 0.f, 0.f, 0.f};
#pragma unroll
    for (int k0 = 0; k0 < K; k0 += 32) {
        short8 a = av ? Arow[(k0 >> 3) + lg] : zz;
#pragma unroll
        for (int ct = 0; ct < 4; ct++) {
            int bo = (ct * 16 + lr) * K + k0 + lg * 8;
            short8 bh = *(const short8*)(bth + bo);
            short8 bl = *(const short8*)(btl + bo);
            acc[ct] = __builtin_amdgcn_mfma_f32_16x16x32_bf16(a, bh, acc[ct], 0, 0, 0);
            acc[ct] = __builtin_amdgcn_mfma_f32_16x16x32_bf16(a, bl, acc[ct], 0, 0, 0);
        }
    }
    f32x4 ps[4], pd[4];
    if (DOATT) {
#pragma unroll
        for (int r = 0; r < 4; r++) {
            ps[r] = (f32x4){0.f, 0.f, 0.f, 0.f};
            pd[r] = (f32x4){0.f, 0.f, 0.f, 0.f};
        }
    }
#pragma unroll
    for (int ct = 0; ct < 4; ct++) {
        int col = ct * 16 + lr;
        float bv = bias[col];
        f32x4 ms4, md4;
        if (DOATT) {
            ms4 = ((const f32x4*)ms_g)[col];
            md4 = ((const f32x4*)md_g)[col];
        }
#pragma unroll
        for (int r = 0; r < 4; r++) {
            int m = m0 + lg * 4 + r;
            float o = eluf(acc[ct][r] + bv);
            if (m < NN) {
                if (out) out[(size_t)m * 64 + col] = o;
                if (out16) out16[(size_t)m * 64 + col] = bf1(o);
            }
            if (DOATT) { ps[r] += o * ms4; pd[r] += o * md4; }
        }
    }
    if (DOATT) {
#pragma unroll
        for (int mk = 1; mk < 16; mk <<= 1)
#pragma unroll
            for (int r = 0; r < 4; r++) {
                ps[r][0] += __shfl_xor(ps[r][0], mk, 64);
                ps[r][1] += __shfl_xor(ps[r][1], mk, 64);
                ps[r][2] += __shfl_xor(ps[r][2], mk, 64);
                ps[r][3] += __shfl_xor(ps[r][3], mk, 64);
                pd[r][0] += __shfl_xor(pd[r][0], mk, 64);
                pd[r][1] += __shfl_xor(pd[r][1], mk, 64);
                pd[r][2] += __shfl_xor(pd[r][2], mk, 64);
                pd[r][3] += __shfl_xor(pd[r][3], mk, 64);
            }
        if (lr == 0) {
#pragma unroll
            for (int r = 0; r < 4; r++) {
                int m = m0 + lg * 4 + r;
                if (m < NN) {
                    *(f32x4*)(as_ + (size_t)m * 4) = ps[r];
                    *(f32x4*)(ad_ + (size_t)m * 4) = pd[r];
                }
            }
        }
    }
}

// ---- SAGE mean aggregation (bf16 neighbor gather) + bf16 self copy from h2b ----
__global__ __launch_bounds__(256) void sage_agg3_kernel(
    const unsigned* __restrict__ h2b,
    const int* __restrict__ eoff, const int* __restrict__ sepc,
    uint2* __restrict__ AB) {
    int n = blockIdx.x * 16 + (threadIdx.x >> 4);
    if (n >= NN) return;
    int l = threadIdx.x & 15;
    const uint2* Hb = (const uint2*)h2b;
    float ax = 0.f, ay = 0.f, az = 0.f, aw = 0.f;
    int b = eoff[n], e_end = eoff[n + 1];
    int idx = b;
    int stop = b + ((e_end - b) & ~7);
    if (idx < stop) {
        int sreg[8];
#pragma unroll
        for (int u = 0; u < 8; u++) sreg[u] = sepc[idx + u] & 0xFFFF;
        idx += 8;
        while (true) {
            int sn[8];
            bool more = idx < stop;
            if (more) {
#pragma unroll
                for (int u = 0; u < 8; u++) sn[u] = sepc[idx + u] & 0xFFFF;
            }
#pragma unroll
            for (int u = 0; u < 8; u++) {
                float4 v = bf16x4(Hb[(size_t)sreg[u] * 16 + l]);
                ax += v.x; ay += v.y; az += v.z; aw += v.w;
            }
            if (!more) break;
#pragma unroll
            for (int u = 0; u < 8; u++) sreg[u] = sn[u];
            idx += 8;
        }
    }
    for (; idx < e_end; idx++) {
        float4 v0 = bf16x4(Hb[(size_t)(sepc[idx] & 0xFFFF) * 16 + l]);
        ax += v0.x; ay += v0.y; az += v0.z; aw += v0.w;
    }
    float dg = (float)(e_end - b);
    if (dg < 1.f) dg = 1.f;
    float inv = 1.f / dg;
    AB[(size_t)n * 32 + l] = bfpack4(ax * inv, ay * inv, az * inv, aw * inv);
    AB[(size_t)n * 32 + 16 + l] = Hb[(size_t)n * 16 + l];
}

// ---- fused pool + MLP head: one block per graph -> d_out[192] ----
__global__ __launch_bounds__(256) void pool_mlp_kernel(
    const float* __restrict__ h3, const int* __restrict__ goff,
    const float* __restrict__ lin1W, const float* __restrict__ lin1b,
    const float* __restrict__ lin2W, const float* __restrict__ lin2b,
    const float* __restrict__ telW, const float* __restrict__ telb,
    const float* __restrict__ compW, const float* __restrict__ compb,
    const float* __restrict__ pchW, const float* __restrict__ pchb,
    float* __restrict__ out) {
    __shared__ float red[256];
    __shared__ float g[64], G1[64], G2[64];
    int gi = blockIdx.x, t = threadIdx.x;
    int c = t & 63, li = t >> 6;
    int b = goff[gi], e = goff[gi + 1];
    float sum = 0.f;
    for (int r = b + li; r < e; r += 4) sum += h3[(size_t)r * HID + c];
    red[t] = sum;
    __syncthreads();
    if (t < 64) {
        float v = red[t] + red[t + 64] + red[t + 128] + red[t + 192];
        float cntf = (float)(e - b);
        if (cntf < 1.f) cntf = 1.f;
        g[t] = v / cntf;
    }
    __syncthreads();
    {
        float part = 0.f;
#pragma unroll
        for (int k = li * 16; k < li * 16 + 16; k++) part += g[k] * lin1W[k * 64 + c];
        red[t] = part;
        __syncthreads();
        if (t < 64)
            G1[c] = eluf(red[c] + red[c + 64] + red[c + 128] + red[c + 192] + lin1b[c]);
        __syncthreads();
    }
    {
        float part = 0.f;
#pragma unroll
        for (int k = li * 16; k < li * 16 + 16; k++) part += G1[k] * lin2W[k * 64 + c];
        red[t] = part;
        __syncthreads();
        if (t < 64)
            G2[c] = red[c] + red[c + 64] + red[c + 128] + red[c + 192] + lin2b[c];
        __syncthreads();
    }
    if (t < 192) {
        int h = t >> 6, k = t & 63;
        const float* W = (h == 0) ? telW : ((h == 1) ? compW : pchW);
        red[t] = G2[k] * W[k];
    }
    __syncthreads();
    if (t < 3) {
        float acc = 0.f;
        for (int k = 0; k < 64; k++) acc += red[t * 64 + k];
        float bb = (t == 0) ? telb[0] : ((t == 1) ? compb[0] : pchb[0]);
        out[t * 64 + gi] = acc + bb;
    }
}

extern "C" void kernel_launch(void* const* d_in, const int* in_sizes, int n_in,
                              void* d_out, int out_size, void* d_ws, size_t ws_size,
                              hipStream_t stream) {
    const float* x        = (const float*)d_in[0];
    const float* EA       = (const float*)d_in[1];
    const float* node_emb = (const float*)d_in[2];
    const float* edge_W   = (const float*)d_in[3];
    const float* edge_b   = (const float*)d_in[4];
    const float* W1       = (const float*)d_in[5];
    const float* as1      = (const float*)d_in[6];
    const float* ad1      = (const float*)d_in[7];
    const float* ae1      = (const float*)d_in[8];
    const float* leW1     = (const float*)d_in[9];
    const float* b1       = (const float*)d_in[10];
    const float* W2       = (const float*)d_in[11];
    const float* as2      = (const float*)d_in[12];
    const float* ad2      = (const float*)d_in[13];
    const float* ae2      = (const float*)d_in[14];
    const float* leW2     = (const float*)d_in[15];
    const float* b2       = (const float*)d_in[16];
    const float* sage_Wl  = (const float*)d_in[17];
    const float* sage_bl  = (const float*)d_in[18];
    const float* sage_Wr  = (const float*)d_in[19];
    const float* lin1_W   = (const float*)d_in[20];
    const float* lin1_b   = (const float*)d_in[21];
    const float* lin2_W   = (const float*)d_in[22];
    const float* lin2_b   = (const float*)d_in[23];
    const float* tel_W    = (const float*)d_in[24];
    const float* tel_b    = (const float*)d_in[25];
    const float* comp_W   = (const float*)d_in[26];
    const float* comp_b   = (const float*)d_in[27];
    const float* pch_W    = (const float*)d_in[28];
    const float* pch_b    = (const float*)d_in[29];
    const int* edge_index = (const int*)d_in[30];
    const int* batch      = (const int*)d_in[31];
    const int* node_type  = (const int*)d_in[32];
    float* outp = (float*)d_out;

    const int* srcp = edge_index;
    const int* dstp = edge_index + NE;

    float* wf = (float*)d_ws;
    constexpr size_t OFF_H3    = 0;                               // N*64
    constexpr size_t OFF_AGG   = OFF_H3 + (size_t)NN * 64;        // N*512 region (bf16 A / AB)
    constexpr size_t OFF_REC   = OFF_AGG + (size_t)NN * 512;      // E*8 (32B records)
    constexpr size_t OFF_AS    = OFF_REC + (size_t)NE * 8;        // N*4
    constexpr size_t OFF_AD    = OFF_AS + (size_t)NN * 4;         // N*4
    constexpr size_t OFF_SMALL = OFF_AD + (size_t)NN * 4;         // 4096
    constexpr size_t OFF_BT    = OFF_SMALL + 4096;                // 45056 floats
    constexpr size_t OFF_XB    = OFF_BT + 45056;                  // N*32 (uint = bf16x2)
    constexpr size_t OFF_H1B   = OFF_XB + (size_t)NN * 32;        // N*32
    constexpr size_t OFF_H2B   = OFF_H1B + (size_t)NN * 32;       // N*32
    constexpr size_t F_TOTAL   = OFF_H2B + (size_t)NN * 32;

    int* wi   = (int*)(wf + F_TOTAL);
    int* cnt  = wi;                        // N*8 (padded: 1 counter / 32B)
    int* rank = wi + NN * 8;               // E
    int* eoff = rank + NE;                 // N+2
    int* sepc = eoff + (NN + 2);           // E compact sep
    int* goff = sepc + NE;                 // NG+1
    int* bsum = goff + (NG + 1);           // 64

    float* h3    = wf + OFF_H3;
    float* aggb  = wf + OFF_AGG;
    uint4* recs  = (uint4*)(wf + OFF_REC);
    float* as_   = wf + OFF_AS;
    float* ad_   = wf + OFF_AD;
    float* S     = wf + OFF_SMALL;
    unsigned short* BT = (unsigned short*)(wf + OFF_BT);
    unsigned* xb  = (unsigned*)(wf + OFF_XB);
    unsigned short* h1b = (unsigned short*)(wf + OFF_H1B);
    unsigned short* h2b = (unsigned short*)(wf + OFF_H2B);

    hipMemsetAsync(S + S_EAS, 0, 16 * sizeof(float), stream);   // EA colsum accum
    hipMemsetAsync(cnt, 0, NN * 8 * sizeof(int), stream);       // padded counters

    cm_prepw_kernel<<<B_TOT, 256, 0, stream>>>(
        dstp, EA, cnt, rank, W1, W2, sage_Wl, sage_Wr, node_emb,
        leW1, ae1, leW2, ae2, edge_W, edge_b, as1, ad1, as2, ad2, batch,
        x, node_emb, node_type, BT, S, goff, as_, ad_, xb);

    scan_blocks_kernel<<<(NN + 1023) / 1024, 1024, 0, stream>>>(cnt, eoff, bsum);
    scanadd_kernel<<<119, 256, 0, stream>>>(bsum, eoff, S);

    scatter_proj_kernel<<<(NE + 511) / 512, 256, 0, stream>>>(
        srcp, dstp, EA, S, as_, ad_, node_type, eoff, rank, recs);

    // ----- GAT layer 1 -----
    agg_gat1_kernel<<<(NN + 3) / 4, 256, 0, stream>>>(
        eoff, recs, xb, node_type, as_, ad_, S, (uint2*)aggb);
    gemm_mfma_kernel<320, true><<<(NN + 63) / 64, 256, 0, stream>>>(
        (const unsigned*)aggb, BT + BT1H, BT + BT1L, b1, nullptr, h1b,
        S + S_MS2, S + S_MD2, as_, ad_);

    // ----- GAT layer 2 -----
    score2_kernel<<<NE / 256, 256, 0, stream>>>(recs, as_, ad_, sepc);
    agg_gat2_kernel<<<(NN + 3) / 4, 256, 0, stream>>>(
        eoff, recs, (const unsigned*)h1b, as_, ad_, S, (uint2*)aggb);
    gemm_mfma_kernel<256, false><<<(NN + 63) / 64, 256, 0, stream>>>(
        (const unsigned*)aggb, BT + BT2H, BT + BT2L, b2, nullptr, h2b,
        nullptr, nullptr, nullptr, nullptr);

    // ----- SAGE -----
    sage_agg3_kernel<<<(NN + 15) / 16, 256, 0, stream>>>(
        (const unsigned*)h2b, eoff, sepc, (uint2*)aggb);
    gemm_mfma_kernel<128, false><<<(NN + 63) / 64, 256, 0, stream>>>(
        (const unsigned*)aggb, BT + BT3H, BT + BT3L, sage_bl, h3, nullptr,
        nullptr, nullptr, nullptr, nullptr);

    // ----- fused pool + MLP head -----
    pool_mlp_kernel<<<NG, 256, 0, stream>>>(h3, goff, lin1_W, lin1_b, lin2_W, lin2_b,
                                            tel_W, tel_b, comp_W, comp_b, pch_W, pch_b, outp);
}

// Round 10
// 364.819 us; speedup vs baseline: 1.0565x; 1.0565x over previous
//
#include <hip/hip_runtime.h>
#include <hip/hip_fp16.h>
#include <math.h>

#define NN 30000          // nodes
#define NE 480000         // edges
#define FEA 16            // edge feature dim
#define HID 64
#define NG 64             // graphs
#define LEAKK 0.2f

// ---- small-constant region layout (float offsets) ----
#define S_AEL1   0    // 4: raw SUM over edges of a_e1 (scale by 1/NE on read)
#define S_AEL2   4    // 4: raw SUM over edges of a_e2
#define S_KF1    16   // 64  (K1 [16,4])
#define S_C1     80   // 4
#define S_KF2    88   // 64
#define S_C2     152  // 4
#define S_MS1    160  // 512 (Ms1 [128,4])
#define S_MD1    672  // 512
#define S_MS2    1184 // 256 (Ms2 [64,4])
#define S_MD2    1440 // 256
#define S_EAS    1700 // 16: EA column sums (atomic accum)

// ---- BT (transposed bf16 hi/lo weight) region layout (ushort offsets) ----
#define BT1H 0        // 64*320
#define BT1L 20480
#define BT2H 40960    // 64*256
#define BT2L 57344
#define BT3H 73728    // 64*128
#define BT3L 81920    // total 90112 ushorts == 45056 floats

typedef __attribute__((ext_vector_type(8))) short short8;
typedef __attribute__((ext_vector_type(4))) float f32x4;

__device__ __forceinline__ float eluf(float v) { return v > 0.f ? v : expm1f(v); }
__device__ __forceinline__ float leakyf(float v) { return v >= 0.f ? v : LEAKK * v; }
__device__ __forceinline__ void fma4(float4& a, float w, const float4& x) {
    a.x += w * x.x; a.y += w * x.y; a.z += w * x.z; a.w += w * x.w;
}
// pack two floats into bf16x2 (RNE)
__device__ __forceinline__ unsigned bf16pack(float a, float b) {
    unsigned ua = __float_as_uint(a), ub = __float_as_uint(b);
    ua = (ua + 0x7FFFu + ((ua >> 16) & 1u)) >> 16;
    ub = (ub + 0x7FFFu + ((ub >> 16) & 1u)) >> 16;
    return ua | (ub << 16);
}
__device__ __forceinline__ unsigned short bf1(float v) {
    unsigned u = __float_as_uint(v);
    return (unsigned short)((u + 0x7FFFu + ((u >> 16) & 1u)) >> 16);
}
__device__ __forceinline__ float bf1tof(unsigned short h) {
    return __uint_as_float(((unsigned)h) << 16);
}
__device__ __forceinline__ uint2 bfpack4(float a, float b, float c, float d) {
    return make_uint2(bf16pack(a, b), bf16pack(c, d));
}
// unpack 4 bf16 (uint2) -> float4
__device__ __forceinline__ float4 bf16x4(uint2 p) {
    float4 r;
    r.x = __uint_as_float(p.x << 16);
    r.y = __uint_as_float(p.x & 0xFFFF0000u);
    r.z = __uint_as_float(p.y << 16);
    r.w = __uint_as_float(p.y & 0xFFFF0000u);
    return r;
}
// fp16 pack/unpack
__device__ __forceinline__ unsigned h2pack(float a, float b) {
    __half2 h = __floats2half2_rn(a, b);
    return *(unsigned*)&h;
}
__device__ __forceinline__ float2 h2unpack(unsigned u) {
    __half2 h = *(__half2*)&u;
    return __half22float2(h);
}
__device__ __forceinline__ float4 h4tof(uint2 p) {
    float2 lo = h2unpack(p.x), hi = h2unpack(p.y);
    return make_float4(lo.x, lo.y, hi.x, hi.y);
}
__device__ __forceinline__ float4 escore4(float4 a, float4 b, float4 c) {
    float4 r;
    r.x = expf(leakyf(a.x + b.x + c.x));
    r.y = expf(leakyf(a.y + b.y + c.y));
    r.z = expf(leakyf(a.z + b.z + c.z));
    r.w = expf(leakyf(a.w + b.w + c.w));
    return r;
}

// Edge record (32B, one HBM sector): [0:8) w1 fp16x4; [8:16) ae2/w2 fp16x4;
// [16:20) sep = src|type<<16; [20:24) dst; [24:32) pad.

// ---- merged prep kernel ----
// blocks 0..175   : BT weight layout
// blocks 176..177 : MS1/MD1
// block  178      : MS2/MD2
// block  179      : KF/C build
// block  180      : goff
// blocks 181..244 : EA column sums (grid-stride, 4x unrolled for 4 in-flight loads)
// blocks 245..    : edge count/rank atomics
__global__ __launch_bounds__(256) void cm_prepw_kernel(
    const int* __restrict__ dst, const float* __restrict__ EA,
    int* __restrict__ cnt, int* __restrict__ rank,
    const float* __restrict__ W1, const float* __restrict__ W2,
    const float* __restrict__ Wl, const float* __restrict__ Wr,
    const float* __restrict__ emb,
    const float* __restrict__ leW1, const float* __restrict__ aew1,
    const float* __restrict__ leW2, const float* __restrict__ aew2,
    const float* __restrict__ edge_W, const float* __restrict__ edge_b,
    const float* __restrict__ as1, const float* __restrict__ ad1,
    const float* __restrict__ as2, const float* __restrict__ ad2,
    const int* __restrict__ batch,
    unsigned short* __restrict__ BT,
    float* __restrict__ S, int* __restrict__ goff) {
    int t = threadIdx.x, bx = blockIdx.x;
    if (bx < 176) {
        int i = bx * 256 + t;
        float v = 0.f;
        int dsti = -1;
        if (i < 16384) {            // BT1 x part: kk = h*64+k
            int kk = i >> 6, c = i & 63;
            int h = kk >> 6, k = kk & 63;
            v = 0.25f * W1[k * 256 + h * 64 + c];
            dsti = BT1H + c * 320 + kk;
        } else if (i < 20480) {     // BT1 emb part: kk = 256 + tau*4 + h
            int j2 = i - 16384;
            int r2 = j2 >> 6, c = j2 & 63;
            int tau = r2 >> 2, h = r2 & 3;
            float acc = 0.f;
            for (int j = 0; j < 64; j++)
                acc += emb[tau * 64 + j] * W1[(64 + j) * 256 + h * 64 + c];
            v = 0.25f * acc;
            dsti = BT1H + c * 320 + 256 + r2;
        } else if (i < 36864) {     // BT2
            int j = i - 20480;
            int kk = j >> 6, c = j & 63;
            int h = kk >> 6, k = kk & 63;
            v = 0.25f * W2[k * 256 + h * 64 + c];
            dsti = BT2H + c * 256 + kk;
        } else if (i < 45056) {     // BT3
            int j = i - 36864;
            int k = j >> 6, c = j & 63;
            v = (k < 64) ? Wl[k * 64 + c] : Wr[(k - 64) * 64 + c];
            dsti = BT3H + c * 128 + k;
        }
        if (dsti >= 0) {
            unsigned short hi = bf1(v);
            unsigned short lo = bf1(v - bf1tof(hi));
            BT[dsti] = hi;
            BT[dsti + 20480 - ((dsti >= BT2H) ? ((dsti >= BT3H) ? 12288 : 4096) : 0)] = lo;
        }
        return;
    }
    if (bx < 178) {                 // MS1/MD1
        int i = (bx - 176) * 256 + t;
        int k = i >> 2, h = i & 3;
        float s = 0.f, d = 0.f;
        for (int c = 0; c < 64; c++) {
            float w = W1[k * 256 + h * 64 + c];
            s += w * as1[h * 64 + c];
            d += w * ad1[h * 64 + c];
        }
        S[S_MS1 + i] = s; S[S_MD1 + i] = d;
        return;
    }
    if (bx == 178) {                // MS2/MD2
        int k = t >> 2, h = t & 3;
        float s = 0.f, d = 0.f;
        for (int c = 0; c < 64; c++) {
            float w = W2[k * 256 + h * 64 + c];
            s += w * as2[h * 64 + c];
            d += w * ad2[h * 64 + c];
        }
        S[S_MS2 + t] = s; S[S_MD2 + t] = d;
        return;
    }
    if (bx == 179) {                // KF/C build
        __shared__ float M1s[256], M2s[256];
        {
            int k = t >> 2, h = t & 3;
            float m1 = 0.f, m2 = 0.f;
            for (int c = 0; c < 64; c++) {
                m1 += leW1[k * 256 + h * 64 + c] * aew1[h * 64 + c];
                m2 += leW2[k * 256 + h * 64 + c] * aew2[h * 64 + c];
            }
            M1s[t] = m1; M2s[t] = m2;
        }
        __syncthreads();
        if (t < 64) {
            int f = t >> 2, h = t & 3;
            float k1 = 0.f, k2 = 0.f;
            for (int k = 0; k < 64; k++) {
                k1 += edge_W[f * 64 + k] * M1s[k * 4 + h];
                k2 += edge_W[f * 64 + k] * M2s[k * 4 + h];
            }
            S[S_KF1 + t] = k1; S[S_KF2 + t] = k2;
        } else if (t < 68) {
            int h = t - 64;
            float c1 = 0.f, c2 = 0.f;
            for (int k = 0; k < 64; k++) {
                c1 += edge_b[k] * M1s[k * 4 + h];
                c2 += edge_b[k] * M2s[k * 4 + h];
            }
            S[S_C1 + h] = c1; S[S_C2 + h] = c2;
        }
        return;
    }
    if (bx == 180) {                // goff
        if (t > NG) return;
        int lo = 0, hi = NN;
        while (lo < hi) {
            int mid = (lo + hi) >> 1;
            if (batch[mid] < t) lo = mid + 1; else hi = mid;
        }
        goff[t] = lo;
        return;
    }
    if (bx < 245) {                 // EA column sums: 64 blocks, 4x unrolled grid-stride
        __shared__ float4 red4[16];
        int cb = bx - 181;
        int c4 = (t & 3) * 4;
        int r0 = cb * 64 + (t >> 2);
        float4 a0 = {0, 0, 0, 0}, a1 = a0, a2 = a0, a3 = a0;
        for (int r = r0; r < NE; r += 16384) {
            int r1 = r + 4096, r2 = r + 8192, r3 = r + 12288;
            float4 v0 = *(const float4*)(EA + (size_t)r * FEA + c4);
            float4 v1 = (r1 < NE) ? *(const float4*)(EA + (size_t)r1 * FEA + c4)
                                  : make_float4(0, 0, 0, 0);
            float4 v2 = (r2 < NE) ? *(const float4*)(EA + (size_t)r2 * FEA + c4)
                                  : make_float4(0, 0, 0, 0);
            float4 v3 = (r3 < NE) ? *(const float4*)(EA + (size_t)r3 * FEA + c4)
                                  : make_float4(0, 0, 0, 0);
            a0.x += v0.x; a0.y += v0.y; a0.z += v0.z; a0.w += v0.w;
            a1.x += v1.x; a1.y += v1.y; a1.z += v1.z; a1.w += v1.w;
            a2.x += v2.x; a2.y += v2.y; a2.z += v2.z; a2.w += v2.w;
            a3.x += v3.x; a3.y += v3.y; a3.z += v3.z; a3.w += v3.w;
        }
        float4 acc;
        acc.x = (a0.x + a1.x) + (a2.x + a3.x);
        acc.y = (a0.y + a1.y) + (a2.y + a3.y);
        acc.z = (a0.z + a1.z) + (a2.z + a3.z);
        acc.w = (a0.w + a1.w) + (a2.w + a3.w);
#pragma unroll
        for (int mask = 4; mask < 64; mask <<= 1) {
            acc.x += __shfl_xor(acc.x, mask, 64);
            acc.y += __shfl_xor(acc.y, mask, 64);
            acc.z += __shfl_xor(acc.z, mask, 64);
            acc.w += __shfl_xor(acc.w, mask, 64);
        }
        int lane = t & 63, wid = t >> 6;
        if (lane < 4) red4[wid * 4 + lane] = acc;
        __syncthreads();
        if (t < 4) {
            float4 a = red4[t], b = red4[4 + t], c = red4[8 + t], d = red4[12 + t];
            atomicAdd(&S[S_EAS + t * 4 + 0], a.x + b.x + c.x + d.x);
            atomicAdd(&S[S_EAS + t * 4 + 1], a.y + b.y + c.y + d.y);
            atomicAdd(&S[S_EAS + t * 4 + 2], a.z + b.z + c.z + d.z);
            atomicAdd(&S[S_EAS + t * 4 + 3], a.w + b.w + c.w + d.w);
        }
        return;
    }
    int e = (bx - 245) * 256 + t;   // count/rank
    if (e < NE) rank[e] = atomicAdd(&cnt[dst[e]], 1);
}

// ---- 30-block scan over degree counts ----
__global__ void scan_blocks_kernel(const int* __restrict__ cnt, int* __restrict__ eoff,
                                   int* __restrict__ bsum) {
    __shared__ int wsum[16];
    int t = threadIdx.x;
    int i = blockIdx.x * 1024 + t;
    int v = (i < NN) ? cnt[i] : 0;
    int lane = t & 63;
    int incl = v;
#pragma unroll
    for (int ofs = 1; ofs < 64; ofs <<= 1) {
        int u = __shfl_up(incl, ofs, 64);
        if (lane >= ofs) incl += u;
    }
    int wid = t >> 6;
    if (lane == 63) wsum[wid] = incl;
    __syncthreads();
    if (t < 16) {
        int s = wsum[t];
#pragma unroll
        for (int ofs = 1; ofs < 16; ofs <<= 1) {
            int u = __shfl_up(s, ofs, 64);
            if (t >= ofs) s += u;
        }
        wsum[t] = s;
    }
    __syncthreads();
    int excl = incl - v + (wid > 0 ? wsum[wid - 1] : 0);
    if (i < NN) eoff[i] = excl;
    if (t == 1023) bsum[blockIdx.x] = excl + v;
}

// ---- merged: blocks 0..117 scan-add; block 118 AEL fold; blocks 119.. a_s/a_d + xb ----
__global__ __launch_bounds__(256) void scanadd_attn_kernel(
    const int* __restrict__ bsum, int* __restrict__ eoff,
    const float* __restrict__ x, const float* __restrict__ node_emb,
    const int* __restrict__ node_type, float* __restrict__ S,
    float* __restrict__ as_, float* __restrict__ ad_, unsigned* __restrict__ xb) {
    __shared__ float xt[64 * 132];
    __shared__ float ms[512], md[512];
    __shared__ int ntS[64];
    int t = threadIdx.x;
    if (blockIdx.x < 118) {
        int j = blockIdx.x >> 2;
        int pref = 0;
        for (int u = 0; u < j; u++) pref += bsum[u];
        int i = blockIdx.x * 256 + t;
        if (i < NN) eoff[i] += pref;
        if (i == 0) eoff[NN] = NE;
        return;
    }
    if (blockIdx.x == 118) {
        // AEL raw sums: sum_e a_e = KF^T * colsum(EA) + NE*C (linearity)
        if (t < 8) {
            int h = t & 3;
            const float* KF = (t < 4) ? (S + S_KF1) : (S + S_KF2);
            const float* C  = (t < 4) ? (S + S_C1)  : (S + S_C2);
            float acc = (float)NE * C[h];
            for (int f = 0; f < 16; f++) acc += S[S_EAS + f] * KF[f * 4 + h];
            S[((t < 4) ? S_AEL1 : S_AEL2) + h] = acc;
        }
        return;
    }
    int n0 = (blockIdx.x - 119) * 64;
    if (t < 64) {
        int n = n0 + t;
        ntS[t] = (n < NN) ? node_type[n] : 0;
    }
    for (int i = t; i < 512; i += 256) { ms[i] = S[S_MS1 + i]; md[i] = S[S_MD1 + i]; }
    __syncthreads();
    for (int i = t; i < 1024; i += 256) {
        int r = i >> 4, c4 = (i & 15) * 4;
        int n = n0 + r;
        float4 f = {0, 0, 0, 0};
        if (n < NN) f = *(const float4*)(x + (size_t)n * 64 + c4);
        *(float4*)&xt[r * 132 + c4] = f;
    }
    for (int i = t; i < 1024; i += 256) {
        int r = i >> 4, c4 = (i & 15) * 4;
        int n = n0 + r;
        float4 f = {0, 0, 0, 0};
        if (n < NN) f = *(const float4*)(node_emb + (size_t)ntS[r] * 64 + c4);
        *(float4*)&xt[r * 132 + 64 + c4] = f;
    }
    __syncthreads();
    for (int i = t; i < 2048; i += 256) {
        int r = i >> 5, u = i & 31;
        int n = n0 + r;
        if (n < NN)
            xb[(size_t)n * 32 + u] = bf16pack(xt[r * 132 + 2 * u], xt[r * 132 + 2 * u + 1]);
    }
    int r = t >> 2, h = t & 3;
    float s = 0.f, d = 0.f;
#pragma unroll 8
    for (int k = 0; k < 128; k++) {
        float xv = xt[r * 132 + k];
        s += xv * ms[k * 4 + h];
        d += xv * md[k * 4 + h];
    }
    int n = n0 + r;
    if (n < NN) { as_[n * 4 + h] = s; ad_[n * 4 + h] = d; }
}

// ---- scatter + edge projection + layer-1 scoring -> ONE 32B record per edge
//      (2 edges/thread for ILP; no atomics, no reductions) ----
__global__ __launch_bounds__(256) void scatter_proj_kernel(
    const int* __restrict__ src, const int* __restrict__ dst,
    const float* __restrict__ EA, const float* __restrict__ S,
    const float* __restrict__ as_, const float* __restrict__ ad_,
    const int* __restrict__ node_type,
    const int* __restrict__ eoff, const int* __restrict__ rank,
    uint4* __restrict__ recs) {
    __shared__ float KF1s[64], KF2s[64], Cs[8];
    int t = threadIdx.x;
    if (t < 64) { KF1s[t] = S[S_KF1 + t]; KF2s[t] = S[S_KF2 + t]; }
    else if (t < 72) { int q = t - 64; Cs[q] = (q < 4) ? S[S_C1 + q] : S[S_C2 + q - 4]; }
    __syncthreads();
    int e0 = blockIdx.x * 512 + t;
#pragma unroll
    for (int u = 0; u < 2; u++) {
        int e = e0 + u * 256;
        if (e < NE) {
            int s = src[e], d = dst[e];
            float a1[4], a2[4];
#pragma unroll
            for (int h = 0; h < 4; h++) { a1[h] = Cs[h]; a2[h] = Cs[4 + h]; }
            const float4* EA4 = (const float4*)(EA + (size_t)e * FEA);
#pragma unroll
            for (int q = 0; q < 4; q++) {
                float4 v = EA4[q];
                float vv[4] = {v.x, v.y, v.z, v.w};
#pragma unroll
                for (int j = 0; j < 4; j++) {
                    int f = q * 4 + j;
#pragma unroll
                    for (int h = 0; h < 4; h++) {
                        a1[h] += vv[j] * KF1s[f * 4 + h];
                        a2[h] += vv[j] * KF2s[f * 4 + h];
                    }
                }
            }
            int pos = eoff[d] + rank[e];
            float4 asv = ((const float4*)as_)[s];
            float4 adv = ((const float4*)ad_)[d];
            float4 w1 = escore4(asv, adv, make_float4(a1[0], a1[1], a1[2], a1[3]));
            uint4 lo = make_uint4(h2pack(w1.x, w1.y), h2pack(w1.z, w1.w),
                                  h2pack(a2[0], a2[1]), h2pack(a2[2], a2[3]));
            uint4 hi = make_uint4((unsigned)(s | (node_type[s] << 16)), (unsigned)d, 0u, 0u);
            recs[2 * pos] = lo;
            recs[2 * pos + 1] = hi;
        }
    }
}

// ---- layer-2 dense scoring, in-place in records; also emits compact sep for sage ----
__global__ __launch_bounds__(256) void score2_kernel(
    uint4* __restrict__ recs,
    const float* __restrict__ as_, const float* __restrict__ ad_,
    int* __restrict__ sepc) {
    int p = blockIdx.x * 256 + threadIdx.x;   // grid exact
    uint2 a2h = ((const uint2*)recs)[4 * p + 1];
    int2 sd = ((const int2*)recs)[4 * p + 2];
    int s = sd.x & 0xFFFF;
    float4 w2 = escore4(((const float4*)as_)[s], ((const float4*)ad_)[sd.y], h4tof(a2h));
    ((uint2*)recs)[4 * p + 1] = make_uint2(h2pack(w2.x, w2.y), h2pack(w2.z, w2.w));
    sepc[p] = sd.x;
}

// ---- layer-1 GAT aggregation: sorted records (w1 fp16) + bf16 x gather + type hist ----
__global__ __launch_bounds__(256) void agg_gat1_kernel(
    const int* __restrict__ eoff, const uint4* __restrict__ recs,
    const unsigned* __restrict__ xb,
    const int* __restrict__ node_type,
    const float* __restrict__ as_, const float* __restrict__ ad_,
    const float* __restrict__ S, uint2* __restrict__ aggb) {
    int n = blockIdx.x * 4 + (threadIdx.x >> 6);
    if (n >= NN) return;
    int lane = threadIdx.x & 63;
    int sub = lane >> 4, ch = lane & 15;
    const uint2* Xb = (const uint2*)xb;
    const int* RI = (const int*)recs;
    const uint2* RW = (const uint2*)recs;
    float4 asn = ((const float4*)as_)[n];
    float4 adn = ((const float4*)ad_)[n];
    float4 a0 = {0, 0, 0, 0}, a1 = a0, a2 = a0, a3 = a0, dn = a0, tw = a0;
    int b = eoff[n], e_end = eoff[n + 1];
    int nE = e_end - b;
    int i = sub;
    for (; i + 4 < nE; i += 8) {
        int p0 = b + i, p1 = p0 + 4;
        int q0 = RI[8 * p0 + 4], q1 = RI[8 * p1 + 4];
        int s0 = q0 & 0xFFFF, t0 = q0 >> 16;
        int s1 = q1 & 0xFFFF, t1 = q1 >> 16;
        float4 w0 = h4tof(RW[4 * p0]), w1 = h4tof(RW[4 * p1]);
        float4 x0 = bf16x4(Xb[(size_t)s0 * 16 + ch]);
        float4 x1 = bf16x4(Xb[(size_t)s1 * 16 + ch]);
        fma4(a0, w0.x, x0); fma4(a1, w0.y, x0); fma4(a2, w0.z, x0); fma4(a3, w0.w, x0);
        fma4(a0, w1.x, x1); fma4(a1, w1.y, x1); fma4(a2, w1.z, x1); fma4(a3, w1.w, x1);
        dn.x += w0.x + w1.x; dn.y += w0.y + w1.y;
        dn.z += w0.z + w1.z; dn.w += w0.w + w1.w;
        if (ch == t0) { tw.x += w0.x; tw.y += w0.y; tw.z += w0.z; tw.w += w0.w; }
        if (ch == t1) { tw.x += w1.x; tw.y += w1.y; tw.z += w1.z; tw.w += w1.w; }
    }
    for (; i < nE; i += 4) {
        int p0 = b + i;
        int q0 = RI[8 * p0 + 4];
        int s0 = q0 & 0xFFFF, t0 = q0 >> 16;
        float4 w0 = h4tof(RW[4 * p0]);
        float4 x0 = bf16x4(Xb[(size_t)s0 * 16 + ch]);
        fma4(a0, w0.x, x0); fma4(a1, w0.y, x0); fma4(a2, w0.z, x0); fma4(a3, w0.w, x0);
        dn.x += w0.x; dn.y += w0.y; dn.z += w0.z; dn.w += w0.w;
        if (ch == t0) { tw.x += w0.x; tw.y += w0.y; tw.z += w0.z; tw.w += w0.w; }
    }
    if (sub == 0) {  // self loop: Sael = raw sum / NE
        const float inv = 1.f / (float)NE;
        float e0 = expf(leakyf(asn.x + adn.x + S[S_AEL1 + 0] * inv));
        float e1 = expf(leakyf(asn.y + adn.y + S[S_AEL1 + 1] * inv));
        float e2 = expf(leakyf(asn.z + adn.z + S[S_AEL1 + 2] * inv));
        float e3 = expf(leakyf(asn.w + adn.w + S[S_AEL1 + 3] * inv));
        float4 xs = bf16x4(Xb[(size_t)n * 16 + ch]);
        fma4(a0, e0, xs); fma4(a1, e1, xs); fma4(a2, e2, xs); fma4(a3, e3, xs);
        dn.x += e0; dn.y += e1; dn.z += e2; dn.w += e3;
        int tn = node_type[n];
        if (ch == tn) { tw.x += e0; tw.y += e1; tw.z += e2; tw.w += e3; }
    }
#pragma unroll
    for (int mask = 16; mask < 64; mask <<= 1) {
        a0.x += __shfl_xor(a0.x, mask, 64); a0.y += __shfl_xor(a0.y, mask, 64);
        a0.z += __shfl_xor(a0.z, mask, 64); a0.w += __shfl_xor(a0.w, mask, 64);
        a1.x += __shfl_xor(a1.x, mask, 64); a1.y += __shfl_xor(a1.y, mask, 64);
        a1.z += __shfl_xor(a1.z, mask, 64); a1.w += __shfl_xor(a1.w, mask, 64);
        a2.x += __shfl_xor(a2.x, mask, 64); a2.y += __shfl_xor(a2.y, mask, 64);
        a2.z += __shfl_xor(a2.z, mask, 64); a2.w += __shfl_xor(a2.w, mask, 64);
        a3.x += __shfl_xor(a3.x, mask, 64); a3.y += __shfl_xor(a3.y, mask, 64);
        a3.z += __shfl_xor(a3.z, mask, 64); a3.w += __shfl_xor(a3.w, mask, 64);
        dn.x += __shfl_xor(dn.x, mask, 64); dn.y += __shfl_xor(dn.y, mask, 64);
        dn.z += __shfl_xor(dn.z, mask, 64); dn.w += __shfl_xor(dn.w, mask, 64);
        tw.x += __shfl_xor(tw.x, mask, 64); tw.y += __shfl_xor(tw.y, mask, 64);
        tw.z += __shfl_xor(tw.z, mask, 64); tw.w += __shfl_xor(tw.w, mask, 64);
    }
    if (sub == 0) {
        float i0 = 1.f / dn.x, i1 = 1.f / dn.y, i2 = 1.f / dn.z, i3 = 1.f / dn.w;
        uint2* A2 = aggb + (size_t)n * 80;   // 320 bf16 per node
        A2[ch]      = bfpack4(a0.x * i0, a0.y * i0, a0.z * i0, a0.w * i0);
        A2[16 + ch] = bfpack4(a1.x * i1, a1.y * i1, a1.z * i1, a1.w * i1);
        A2[32 + ch] = bfpack4(a2.x * i2, a2.y * i2, a2.z * i2, a2.w * i2);
        A2[48 + ch] = bfpack4(a3.x * i3, a3.y * i3, a3.z * i3, a3.w * i3);
        A2[64 + ch] = bfpack4(tw.x * i0, tw.y * i1, tw.z * i2, tw.w * i3);
    }
}

// ---- layer-2 GAT aggregation: sorted records (w2 fp16) + bf16 h1 gather ----
__global__ __launch_bounds__(256) void agg_gat2_kernel(
    const int* __restrict__ eoff, const uint4* __restrict__ recs,
    const unsigned* __restrict__ h1b,
    const float* __restrict__ as_, const float* __restrict__ ad_,
    const float* __restrict__ S, uint2* __restrict__ aggb) {
    int n = blockIdx.x * 4 + (threadIdx.x >> 6);
    if (n >= NN) return;
    int lane = threadIdx.x & 63;
    int sub = lane >> 4, ch = lane & 15;
    const uint2* Xb = (const uint2*)h1b;
    const int* RI = (const int*)recs;
    const uint2* RW = (const uint2*)recs;
    float4 asn = ((const float4*)as_)[n];
    float4 adn = ((const float4*)ad_)[n];
    float4 a0 = {0, 0, 0, 0}, a1 = a0, a2 = a0, a3 = a0, dn = a0;
    int b = eoff[n], e = eoff[n + 1];
    int nE = e - b;
    int i = sub;
    for (; i + 4 < nE; i += 8) {
        int p0 = b + i, p1 = p0 + 4;
        int s0 = RI[8 * p0 + 4] & 0xFFFF, s1 = RI[8 * p1 + 4] & 0xFFFF;
        float4 w0 = h4tof(RW[4 * p0 + 1]), w1 = h4tof(RW[4 * p1 + 1]);
        float4 x0 = bf16x4(Xb[(size_t)s0 * 16 + ch]);
        float4 x1 = bf16x4(Xb[(size_t)s1 * 16 + ch]);
        fma4(a0, w0.x, x0); fma4(a1, w0.y, x0); fma4(a2, w0.z, x0); fma4(a3, w0.w, x0);
        fma4(a0, w1.x, x1); fma4(a1, w1.y, x1); fma4(a2, w1.z, x1); fma4(a3, w1.w, x1);
        dn.x += w0.x + w1.x; dn.y += w0.y + w1.y;
        dn.z += w0.z + w1.z; dn.w += w0.w + w1.w;
    }
    for (; i < nE; i += 4) {
        int p0 = b + i;
        int s0 = RI[8 * p0 + 4] & 0xFFFF;
        float4 w0 = h4tof(RW[4 * p0 + 1]);
        float4 x0 = bf16x4(Xb[(size_t)s0 * 16 + ch]);
        fma4(a0, w0.x, x0); fma4(a1, w0.y, x0); fma4(a2, w0.z, x0); fma4(a3, w0.w, x0);
        dn.x += w0.x; dn.y += w0.y; dn.z += w0.z; dn.w += w0.w;
    }
    if (sub == 0) {  // self loop
        const float inv = 1.f / (float)NE;
        float e0 = expf(leakyf(asn.x + adn.x + S[S_AEL2 + 0] * inv));
        float e1 = expf(leakyf(asn.y + adn.y + S[S_AEL2 + 1] * inv));
        float e2 = expf(leakyf(asn.z + adn.z + S[S_AEL2 + 2] * inv));
        float e3 = expf(leakyf(asn.w + adn.w + S[S_AEL2 + 3] * inv));
        float4 xs = bf16x4(Xb[(size_t)n * 16 + ch]);
        fma4(a0, e0, xs); fma4(a1, e1, xs); fma4(a2, e2, xs); fma4(a3, e3, xs);
        dn.x += e0; dn.y += e1; dn.z += e2; dn.w += e3;
    }
#pragma unroll
    for (int mask = 16; mask < 64; mask <<= 1) {
        a0.x += __shfl_xor(a0.x, mask, 64); a0.y += __shfl_xor(a0.y, mask, 64);
        a0.z += __shfl_xor(a0.z, mask, 64); a0.w += __shfl_xor(a0.w, mask, 64);
        a1.x += __shfl_xor(a1.x, mask, 64); a1.y += __shfl_xor(a1.y, mask, 64);
        a1.z += __shfl_xor(a1.z, mask, 64); a1.w += __shfl_xor(a1.w, mask, 64);
        a2.x += __shfl_xor(a2.x, mask, 64); a2.y += __shfl_xor(a2.y, mask, 64);
        a2.z += __shfl_xor(a2.z, mask, 64); a2.w += __shfl_xor(a2.w, mask, 64);
        a3.x += __shfl_xor(a3.x, mask, 64); a3.y += __shfl_xor(a3.y, mask, 64);
        a3.z += __shfl_xor(a3.z, mask, 64); a3.w += __shfl_xor(a3.w, mask, 64);
        dn.x += __shfl_xor(dn.x, mask, 64); dn.y += __shfl_xor(dn.y, mask, 64);
        dn.z += __shfl_xor(dn.z, mask, 64); dn.w += __shfl_xor(dn.w, mask, 64);
    }
    if (sub == 0) {
        float i0 = 1.f / dn.x, i1 = 1.f / dn.y, i2 = 1.f / dn.z, i3 = 1.f / dn.w;
        uint2* A2 = aggb + (size_t)n * 64;   // 256 bf16 per node
        A2[ch]      = bfpack4(a0.x * i0, a0.y * i0, a0.z * i0, a0.w * i0);
        A2[16 + ch] = bfpack4(a1.x * i1, a1.y * i1, a1.z * i1, a1.w * i1);
        A2[32 + ch] = bfpack4(a2.x * i2, a2.y * i2, a2.z * i2, a2.w * i2);
        A2[48 + ch] = bfpack4(a3.x * i3, a3.y * i3, a3.z * i3, a3.w * i3);
    }
}

// ---- MFMA GEMM: out[M,64] = elu(A@B + bias). A bf16 rows; B = BT hi/lo bf16 (transposed).
template <int K, bool DOATT>
__global__ __launch_bounds__(256) void gemm_mfma_kernel(
    const unsigned* __restrict__ A, const unsigned short* __restrict__ bth,
    const unsigned short* __restrict__ btl,
    const float* __restrict__ bias, float* __restrict__ out,
    unsigned short* __restrict__ out16,
    const float* __restrict__ ms_g, const float* __restrict__ md_g,
    float* __restrict__ as_, float* __restrict__ ad_) {
    int t = threadIdx.x;
    int w = t >> 6, l = t & 63;
    int lr = l & 15, lg = l >> 4;
    int m0 = blockIdx.x * 64 + w * 16;
    int am = m0 + lr;
    bool av = am < NN;
    const short8* Arow = (const short8*)A + (size_t)am * (K / 8);
    short8 zz = {0, 0, 0, 0, 0, 0, 0, 0};
    f32x4 acc[4];
#pragma unroll
    for (int ct = 0; ct < 4; ct++) acc[ct] = (f32x4){0.f, 0.f, 0.f, 0.f};
#pragma unroll
    for (int k0 = 0; k0 < K; k0 += 32) {
        short8 a = av ? Arow[(k0 >> 3) + lg] : zz;
#pragma unroll
        for (int ct = 0; ct < 4; ct++) {
            int bo = (ct * 16 + lr) * K + k0 + lg * 8;
            short8 bh = *(const short8*)(bth + bo);
            short8 bl = *(const short8*)(btl + bo);
            acc[ct] = __builtin_amdgcn_mfma_f32_16x16x32_bf16(a, bh, acc[ct], 0, 0, 0);
            acc[ct] = __builtin_amdgcn_mfma_f32_16x16x32_bf16(a, bl, acc[ct], 0, 0, 0);
        }
    }
    f32x4 ps[4], pd[4];
    if (DOATT) {
#pragma unroll
        for (int r = 0; r < 4; r++) {
            ps[r] = (f32x4){0.f, 0.f, 0.f, 0.f};
            pd[r] = (f32x4){0.f, 0.f, 0.f, 0.f};
        }
    }
#pragma unroll
    for (int ct = 0; ct < 4; ct++) {
        int col = ct * 16 + lr;
        float bv = bias[col];
        f32x4 ms4, md4;
        if (DOATT) {
            ms4 = ((const f32x4*)ms_g)[col];
            md4 = ((const f32x4*)md_g)[col];
        }
#pragma unroll
        for (int r = 0; r < 4; r++) {
            int m = m0 + lg * 4 + r;
            float o = eluf(acc[ct][r] + bv);
            if (m < NN) {
                if (out) out[(size_t)m * 64 + col] = o;
                if (out16) out16[(size_t)m * 64 + col] = bf1(o);
            }
            if (DOATT) { ps[r] += o * ms4; pd[r] += o * md4; }
        }
    }
    if (DOATT) {
#pragma unroll
        for (int mk = 1; mk < 16; mk <<= 1)
#pragma unroll
            for (int r = 0; r < 4; r++) {
                ps[r][0] += __shfl_xor(ps[r][0], mk, 64);
                ps[r][1] += __shfl_xor(ps[r][1], mk, 64);
                ps[r][2] += __shfl_xor(ps[r][2], mk, 64);
                ps[r][3] += __shfl_xor(ps[r][3], mk, 64);
                pd[r][0] += __shfl_xor(pd[r][0], mk, 64);
                pd[r][1] += __shfl_xor(pd[r][1], mk, 64);
                pd[r][2] += __shfl_xor(pd[r][2], mk, 64);
                pd[r][3] += __shfl_xor(pd[r][3], mk, 64);
            }
        if (lr == 0) {
#pragma unroll
            for (int r = 0; r < 4; r++) {
                int m = m0 + lg * 4 + r;
                if (m < NN) {
                    *(f32x4*)(as_ + (size_t)m * 4) = ps[r];
                    *(f32x4*)(ad_ + (size_t)m * 4) = pd[r];
                }
            }
        }
    }
}

// ---- SAGE mean aggregation (bf16 neighbor gather) + bf16 self copy from h2b ----
__global__ __launch_bounds__(256) void sage_agg3_kernel(
    const unsigned* __restrict__ h2b,
    const int* __restrict__ eoff, const int* __restrict__ sepc,
    uint2* __restrict__ AB) {
    int n = blockIdx.x * 16 + (threadIdx.x >> 4);
    if (n >= NN) return;
    int l = threadIdx.x & 15;
    const uint2* Hb = (const uint2*)h2b;
    float ax = 0.f, ay = 0.f, az = 0.f, aw = 0.f;
    int b = eoff[n], e_end = eoff[n + 1];
    int idx = b;
    int stop = b + ((e_end - b) & ~7);
    if (idx < stop) {
        int sreg[8];
#pragma unroll
        for (int u = 0; u < 8; u++) sreg[u] = sepc[idx + u] & 0xFFFF;
        idx += 8;
        while (true) {
            int sn[8];
            bool more = idx < stop;
            if (more) {
#pragma unroll
                for (int u = 0; u < 8; u++) sn[u] = sepc[idx + u] & 0xFFFF;
            }
#pragma unroll
            for (int u = 0; u < 8; u++) {
                float4 v = bf16x4(Hb[(size_t)sreg[u] * 16 + l]);
                ax += v.x; ay += v.y; az += v.z; aw += v.w;
            }
            if (!more) break;
#pragma unroll
            for (int u = 0; u < 8; u++) sreg[u] = sn[u];
            idx += 8;
        }
    }
    for (; idx < e_end; idx++) {
        float4 v0 = bf16x4(Hb[(size_t)(sepc[idx] & 0xFFFF) * 16 + l]);
        ax += v0.x; ay += v0.y; az += v0.z; aw += v0.w;
    }
    float dg = (float)(e_end - b);
    if (dg < 1.f) dg = 1.f;
    float inv = 1.f / dg;
    AB[(size_t)n * 32 + l] = bfpack4(ax * inv, ay * inv, az * inv, aw * inv);
    AB[(size_t)n * 32 + 16 + l] = Hb[(size_t)n * 16 + l];
}

// ---- fused pool + MLP head: one block per graph -> d_out[192] ----
__global__ __launch_bounds__(256) void pool_mlp_kernel(
    const float* __restrict__ h3, const int* __restrict__ goff,
    const float* __restrict__ lin1W, const float* __restrict__ lin1b,
    const float* __restrict__ lin2W, const float* __restrict__ lin2b,
    const float* __restrict__ telW, const float* __restrict__ telb,
    const float* __restrict__ compW, const float* __restrict__ compb,
    const float* __restrict__ pchW, const float* __restrict__ pchb,
    float* __restrict__ out) {
    __shared__ float red[256];
    __shared__ float g[64], G1[64], G2[64];
    int gi = blockIdx.x, t = threadIdx.x;
    int c = t & 63, li = t >> 6;
    int b = goff[gi], e = goff[gi + 1];
    float sum = 0.f;
    for (int r = b + li; r < e; r += 4) sum += h3[(size_t)r * HID + c];
    red[t] = sum;
    __syncthreads();
    if (t < 64) {
        float v = red[t] + red[t + 64] + red[t + 128] + red[t + 192];
        float cntf = (float)(e - b);
        if (cntf < 1.f) cntf = 1.f;
        g[t] = v / cntf;
    }
    __syncthreads();
    {
        float part = 0.f;
#pragma unroll
        for (int k = li * 16; k < li * 16 + 16; k++) part += g[k] * lin1W[k * 64 + c];
        red[t] = part;
        __syncthreads();
        if (t < 64)
            G1[c] = eluf(red[c] + red[c + 64] + red[c + 128] + red[c + 192] + lin1b[c]);
        __syncthreads();
    }
    {
        float part = 0.f;
#pragma unroll
        for (int k = li * 16; k < li * 16 + 16; k++) part += G1[k] * lin2W[k * 64 + c];
        red[t] = part;
        __syncthreads();
        if (t < 64)
            G2[c] = red[c] + red[c + 64] + red[c + 128] + red[c + 192] + lin2b[c];
        __syncthreads();
    }
    if (t < 192) {
        int h = t >> 6, k = t & 63;
        const float* W = (h == 0) ? telW : ((h == 1) ? compW : pchW);
        red[t] = G2[k] * W[k];
    }
    __syncthreads();
    if (t < 3) {
        float acc = 0.f;
        for (int k = 0; k < 64; k++) acc += red[t * 64 + k];
        float bb = (t == 0) ? telb[0] : ((t == 1) ? compb[0] : pchb[0]);
        out[t * 64 + gi] = acc + bb;
    }
}

extern "C" void kernel_launch(void* const* d_in, const int* in_sizes, int n_in,
                              void* d_out, int out_size, void* d_ws, size_t ws_size,
                              hipStream_t stream) {
    const float* x        = (const float*)d_in[0];
    const float* EA       = (const float*)d_in[1];
    const float* node_emb = (const float*)d_in[2];
    const float* edge_W   = (const float*)d_in[3];
    const float* edge_b   = (const float*)d_in[4];
    const float* W1       = (const float*)d_in[5];
    const float* as1      = (const float*)d_in[6];
    const float* ad1      = (const float*)d_in[7];
    const float* ae1      = (const float*)d_in[8];
    const float* leW1     = (const float*)d_in[9];
    const float* b1       = (const float*)d_in[10];
    const float* W2       = (const float*)d_in[11];
    const float* as2      = (const float*)d_in[12];
    const float* ad2      = (const float*)d_in[13];
    const float* ae2      = (const float*)d_in[14];
    const float* leW2     = (const float*)d_in[15];
    const float* b2       = (const float*)d_in[16];
    const float* sage_Wl  = (const float*)d_in[17];
    const float* sage_bl  = (const float*)d_in[18];
    const float* sage_Wr  = (const float*)d_in[19];
    const float* lin1_W   = (const float*)d_in[20];
    const float* lin1_b   = (const float*)d_in[21];
    const float* lin2_W   = (const float*)d_in[22];
    const float* lin2_b   = (const float*)d_in[23];
    const float* tel_W    = (const float*)d_in[24];
    const float* tel_b    = (const float*)d_in[25];
    const float* comp_W   = (const float*)d_in[26];
    const float* comp_b   = (const float*)d_in[27];
    const float* pch_W    = (const float*)d_in[28];
    const float* pch_b    = (const float*)d_in[29];
    const int* edge_index = (const int*)d_in[30];
    const int* batch      = (const int*)d_in[31];
    const int* node_type  = (const int*)d_in[32];
    float* outp = (float*)d_out;

    const int* srcp = edge_index;
    const int* dstp = edge_index + NE;

    float* wf = (float*)d_ws;
    constexpr size_t OFF_H3    = 0;                               // N*64
    constexpr size_t OFF_AGG   = OFF_H3 + (size_t)NN * 64;        // N*512 region (bf16 A / AB)
    constexpr size_t OFF_REC   = OFF_AGG + (size_t)NN * 512;      // E*8 (32B records)
    constexpr size_t OFF_AS    = OFF_REC + (size_t)NE * 8;        // N*4
    constexpr size_t OFF_AD    = OFF_AS + (size_t)NN * 4;         // N*4
    constexpr size_t OFF_SMALL = OFF_AD + (size_t)NN * 4;         // 4096
    constexpr size_t OFF_BT    = OFF_SMALL + 4096;                // 45056 floats
    constexpr size_t OFF_XB    = OFF_BT + 45056;                  // N*32 (uint = bf16x2)
    constexpr size_t OFF_H1B   = OFF_XB + (size_t)NN * 32;        // N*32
    constexpr size_t OFF_H2B   = OFF_H1B + (size_t)NN * 32;       // N*32
    constexpr size_t F_TOTAL   = OFF_H2B + (size_t)NN * 32;

    int* wi   = (int*)(wf + F_TOTAL);
    int* cnt  = wi;                        // N
    int* rank = wi + NN;                   // E
    int* eoff = rank + NE;                 // N+2
    int* sepc = eoff + (NN + 2);           // E compact sep
    int* goff = sepc + NE;                 // NG+1
    int* bsum = goff + (NG + 1);           // 64

    float* h3    = wf + OFF_H3;
    float* aggb  = wf + OFF_AGG;
    uint4* recs  = (uint4*)(wf + OFF_REC);
    float* as_   = wf + OFF_AS;
    float* ad_   = wf + OFF_AD;
    float* S     = wf + OFF_SMALL;
    unsigned short* BT = (unsigned short*)(wf + OFF_BT);
    unsigned* xb  = (unsigned*)(wf + OFF_XB);
    unsigned short* h1b = (unsigned short*)(wf + OFF_H1B);
    unsigned short* h2b = (unsigned short*)(wf + OFF_H2B);

    hipMemsetAsync(S + S_EAS, 0, 16 * sizeof(float), stream);   // EA colsum accum
    hipMemsetAsync(cnt, 0, NN * sizeof(int), stream);

    cm_prepw_kernel<<<245 + (NE + 255) / 256, 256, 0, stream>>>(
        dstp, EA, cnt, rank, W1, W2, sage_Wl, sage_Wr, node_emb,
        leW1, ae1, leW2, ae2, edge_W, edge_b, as1, ad1, as2, ad2, batch,
        BT, S, goff);

    scan_blocks_kernel<<<(NN + 1023) / 1024, 1024, 0, stream>>>(cnt, eoff, bsum);
    scanadd_attn_kernel<<<119 + (NN + 63) / 64, 256, 0, stream>>>(
        bsum, eoff, x, node_emb, node_type, S, as_, ad_, xb);

    scatter_proj_kernel<<<(NE + 511) / 512, 256, 0, stream>>>(
        srcp, dstp, EA, S, as_, ad_, node_type, eoff, rank, recs);

    // ----- GAT layer 1 -----
    agg_gat1_kernel<<<(NN + 3) / 4, 256, 0, stream>>>(
        eoff, recs, xb, node_type, as_, ad_, S, (uint2*)aggb);
    gemm_mfma_kernel<320, true><<<(NN + 63) / 64, 256, 0, stream>>>(
        (const unsigned*)aggb, BT + BT1H, BT + BT1L, b1, nullptr, h1b,
        S + S_MS2, S + S_MD2, as_, ad_);

    // ----- GAT layer 2 -----
    score2_kernel<<<NE / 256, 256, 0, stream>>>(recs, as_, ad_, sepc);
    agg_gat2_kernel<<<(NN + 3) / 4, 256, 0, stream>>>(
        eoff, recs, (const unsigned*)h1b, as_, ad_, S, (uint2*)aggb);
    gemm_mfma_kernel<256, false><<<(NN + 63) / 64, 256, 0, stream>>>(
        (const unsigned*)aggb, BT + BT2H, BT + BT2L, b2, nullptr, h2b,
        nullptr, nullptr, nullptr, nullptr);

    // ----- SAGE -----
    sage_agg3_kernel<<<(NN + 15) / 16, 256, 0, stream>>>(
        (const unsigned*)h2b, eoff, sepc, (uint2*)aggb);
    gemm_mfma_kernel<128, false><<<(NN + 63) / 64, 256, 0, stream>>>(
        (const unsigned*)aggb, BT + BT3H, BT + BT3L, sage_bl, h3, nullptr,
        nullptr, nullptr, nullptr, nullptr);

    // ----- fused pool + MLP head -----
    pool_mlp_kernel<<<NG, 256, 0, stream>>>(h3, goff, lin1_W, lin1_b, lin2_W, lin2_b,
                                            tel_W, tel_b, comp_W, comp_b, pch_W, pch_b, outp);
}